// Round 11
// baseline (155.771 us; speedup 1.0000x reference)
//
#include <hip/hip_runtime.h>
#include <hip/hip_bf16.h>
#include <cstdint>
#include <cstddef>

// Shapes: b=8, n=8, p=q=64, x=32, y=32, d=8  -> xyd = x*256+y*8+d in [0,8192)
// Q,K,V: [bn=64][64][8192] fp32.  out: [b][p][xyd][n] fp32 (transposed).
// scores[bn][p][q] = dot_k(Q,K)/1024 -> softmax over q -> out = attn @ V.
//
// R10 lesson: the lever is the chip-wide concurrent address frontier.
// ch-fastest grid (32 ch x 16 bn resident) = 32 streams -> 93us (+21%).
// This round: kchunks=64, BK=128 -> resident = 64 ch x 8 bn = 16 streams.

typedef __attribute__((ext_vector_type(4))) float f32x4;
typedef __attribute__((ext_vector_type(8))) short bf16x8;
typedef __attribute__((ext_vector_type(4))) short shortx4;

__device__ __forceinline__ unsigned short f2bf(float x) {
    unsigned int u = __builtin_bit_cast(unsigned int, x);
    u += 0x7FFFu + ((u >> 16) & 1u);     // RTNE
    return (unsigned short)(u >> 16);
}

__device__ __forceinline__ bf16x8 pack8(float4 lo, float4 hi) {
    bf16x8 f;
    f[0] = (short)f2bf(lo.x); f[1] = (short)f2bf(lo.y);
    f[2] = (short)f2bf(lo.z); f[3] = (short)f2bf(lo.w);
    f[4] = (short)f2bf(hi.x); f[5] = (short)f2bf(hi.y);
    f[6] = (short)f2bf(hi.z); f[7] = (short)f2bf(hi.w);
    return f;
}

// ---------------- Kernel A: partial QK^T via bf16 MFMA, BK=128 ----
// grid (ch FASTEST, bn=64), 1024 threads = 16 waves.
// Per 128-k phase: thread loads 2 float4 Q + 2 float4 K (wave = 4 rows x 512B
// contiguous), bf16-pack into XOR-swizzled LDS [64][128] tiles, one barrier,
// 4 MFMA k-steps (wave w owns 16x16 output tile (w>>2, w&3)).
// partial[ch][bn][p][q]
__global__ __launch_bounds__(1024) void qk_mfma_kernel(
    const float* __restrict__ Q, const float* __restrict__ K,
    float* __restrict__ partial, int clen)
{
    __shared__ unsigned short Qs[64 * 128];   // 16 KiB bf16 [row][k]
    __shared__ unsigned short Ks[64 * 128];   // 16 KiB

    const int ch   = blockIdx.x;        // FASTEST: dense cross-block frontier
    const int bn   = blockIdx.y;
    const int tid  = threadIdx.x;
    const int w    = tid >> 6;
    const int lane = tid & 63;
    const int wr   = w >> 2;            // p-tile 0..3
    const int wc   = w & 3;             // q-tile 0..3
    const int frow = lane & 15;
    const int kg   = lane >> 4;         // 0..3

    const float* Qb = Q + (size_t)bn * 64 * 8192 + (size_t)ch * clen;
    const float* Kb = K + (size_t)bn * 64 * 8192 + (size_t)ch * clen;

    const int srow = tid >> 4;          // staged row 0..63
    const int slot = tid & 15;          // 16B bf16 slot (= 32B fp32 in global)
    const int nph  = clen >> 7;         // phases of 128 k (1 when kchunks=64)

    f32x4 acc = (f32x4)(0.f);
    const int arow = wr * 16 + frow;
    const int brow = wc * 16 + frow;

    #pragma unroll 1
    for (int ph = 0; ph < nph; ++ph) {
        const float4* qp = (const float4*)(Qb + (size_t)srow * 8192 + ph * 128 + slot * 8);
        const float4* kp = (const float4*)(Kb + (size_t)srow * 8192 + ph * 128 + slot * 8);
        const float4 q0 = qp[0], q1 = qp[1];
        const float4 k0 = kp[0], k1 = kp[1];
        if (ph) __syncthreads();        // protect prior phase's LDS reads
        // 16B-slot swizzle: slot' = slot ^ (row&7)  (16 slots of 16B per row)
        const int sl = slot ^ (srow & 7);
        *(bf16x8*)(Qs + srow * 128 + sl * 8) = pack8(q0, q1);
        *(bf16x8*)(Ks + srow * 128 + sl * 8) = pack8(k0, k1);
        __syncthreads();
        #pragma unroll
        for (int ks = 0; ks < 4; ++ks) {
            const bf16x8 a = *(const bf16x8*)(Qs + arow * 128 +
                                (((ks * 4 + kg) ^ (arow & 7)) * 8));
            const bf16x8 b = *(const bf16x8*)(Ks + brow * 128 +
                                (((ks * 4 + kg) ^ (brow & 7)) * 8));
            acc = __builtin_amdgcn_mfma_f32_16x16x32_bf16(a, b, acc, 0, 0, 0);
        }
    }

    // D layout: col = lane&15 (q), row = kg*4 + r (p)
    float* pb = partial + ((size_t)ch * 64 + bn) * 4096;
    const int p0 = wr * 16 + kg * 4;
    const int q0 = wc * 16 + frow;
    #pragma unroll
    for (int r = 0; r < 4; ++r)
        pb[(size_t)(p0 + r) * 64 + q0] = acc[r];
}

// ---------------- Kernel B: reduce partials + softmax (unchanged) ----------------
__global__ __launch_bounds__(256) void softmax_kernel(
    float* __restrict__ ws, const unsigned char* __restrict__ mask, int kchunks)
{
    const int row  = blockIdx.x * 4 + (threadIdx.x >> 6);
    const int q    = threadIdx.x & 63;
    float s = 0.f;
    for (int c = 0; c < kchunks; ++c)
        s += ws[((size_t)c * 4096 + row) * 64 + q];
    s *= (1.0f / 1024.0f);
    const int b = row >> 9;
    if (mask[b * 64 + q]) s = -__builtin_inff();
    float m = s;
    #pragma unroll
    for (int off = 32; off; off >>= 1) m = fmaxf(m, __shfl_xor(m, off));
    const float e = __expf(s - m);
    float sum = e;
    #pragma unroll
    for (int off = 32; off; off >>= 1) sum += __shfl_xor(sum, off);
    ws[(size_t)row * 64 + q] = e / sum;
}

// ---------------- Kernel C: PV via bf16 MFMA (unchanged, proven) ----------------
__global__ __launch_bounds__(512, 2) void pv_mfma_kernel(
    const float* __restrict__ V, const float* __restrict__ attn,
    float* __restrict__ out)
{
    __shared__ unsigned char smem[65536];   // phase 1: vt[8][64][64] bf16; phase 2: ob fp32

    const int b     = blockIdx.y;
    const int chunk = blockIdx.x;
    const int tid   = threadIdx.x;
    const int w     = tid >> 6;           // wave = n
    const int lane  = tid & 63;

    const float* Vb = V    + (size_t)(b * 8 + w) * 64 * 8192 + (size_t)chunk * 64;
    const float* Ab = attn + (size_t)(b * 8 + w) * 4096;

    unsigned short* vtn = (unsigned short*)smem + w * 4096;   // this wave's V^T tile

    // ---- stage V chunk -> LDS transposed bf16, swizzled ----
    const int c  = lane >> 2;
    const int qg = lane & 3;
    #pragma unroll
    for (int s = 0; s < 4; ++s) {
        const int q0 = s * 16 + qg * 4;
        const float4 r0 = *(const float4*)&Vb[(size_t)(q0 + 0) * 8192 + c * 4];
        const float4 r1 = *(const float4*)&Vb[(size_t)(q0 + 1) * 8192 + c * 4];
        const float4 r2 = *(const float4*)&Vb[(size_t)(q0 + 2) * 8192 + c * 4];
        const float4 r3 = *(const float4*)&Vb[(size_t)(q0 + 3) * 8192 + c * 4];
        const float v0[4] = {r0.x, r0.y, r0.z, r0.w};
        const float v1[4] = {r1.x, r1.y, r1.z, r1.w};
        const float v2[4] = {r2.x, r2.y, r2.z, r2.w};
        const float v3[4] = {r3.x, r3.y, r3.z, r3.w};
        #pragma unroll
        for (int cc = 0; cc < 4; ++cc) {
            const int row = c * 4 + cc;       // xc within chunk
            shortx4 pk;
            pk.x = (short)f2bf(v0[cc]);
            pk.y = (short)f2bf(v1[cc]);
            pk.z = (short)f2bf(v2[cc]);
            pk.w = (short)f2bf(v3[cc]);
            const int soff = row * 64 + (q0 ^ ((row & 7) << 3) ^ (((row >> 3) & 3) << 4));
            *(shortx4*)(vtn + soff) = pk;
        }
    }

    // ---- A fragments: attn rows, bf16 ----
    const int arow = lane & 15;
    const int q0a  = (lane >> 4) * 8;
    bf16x8 afrag[4][2];
    #pragma unroll
    for (int mt = 0; mt < 4; ++mt) {
        #pragma unroll
        for (int ks = 0; ks < 2; ++ks) {
            const float* ap = Ab + (mt * 16 + arow) * 64 + ks * 32 + q0a;
            const float4 lo = *(const float4*)ap;
            const float4 hi = *(const float4*)(ap + 4);
            afrag[mt][ks] = pack8(lo, hi);
        }
    }

    // ---- MFMA compute ----
    f32x4 acc[4][4];
    #pragma unroll
    for (int mt = 0; mt < 4; ++mt)
        #pragma unroll
        for (int nt = 0; nt < 4; ++nt)
            acc[mt][nt] = (f32x4)(0.f);

    const int bcol = lane & 15;
    const int q0b  = (lane >> 4) * 8;
    #pragma unroll
    for (int nt = 0; nt < 4; ++nt) {
        bf16x8 bfr[2];
        #pragma unroll
        for (int ks = 0; ks < 2; ++ks) {
            const int row  = nt * 16 + bcol;
            const int q0   = ks * 32 + q0b;
            const int soff = row * 64 + (q0 ^ ((row & 7) << 3) ^ (((row >> 3) & 3) << 4));
            bfr[ks] = *(const bf16x8*)(vtn + soff);
        }
        #pragma unroll
        for (int ks = 0; ks < 2; ++ks)
            #pragma unroll
            for (int mt = 0; mt < 4; ++mt)
                acc[mt][nt] = __builtin_amdgcn_mfma_f32_16x16x32_bf16(
                    afrag[mt][ks], bfr[ks], acc[mt][nt], 0, 0, 0);
    }

    // ---- store: D frags -> LDS transpose -> coalesced float4 stores ----
    float* ob = (float*)smem;          // [16 p][64 xc][9 (8n + pad)]
    const int pq = lane >> 4;
    const int pl = tid >> 5;           // 0..15 : p-row for store phase
    const int g  = tid & 31;
    #pragma unroll
    for (int mt = 0; mt < 4; ++mt) {
        __syncthreads();
        #pragma unroll
        for (int nt = 0; nt < 4; ++nt)
            #pragma unroll
            for (int r = 0; r < 4; ++r) {
                const int prow = pq * 4 + r;
                const int xc   = nt * 16 + (lane & 15);
                ob[prow * 576 + xc * 9 + w] = acc[mt][nt][r];
            }
        __syncthreads();
        float* orow = out + (size_t)b * 4194304 + (size_t)(mt * 16 + pl) * 65536
                          + (size_t)chunk * 512;
        #pragma unroll
        for (int u = 0; u < 4; ++u) {
            const int f0 = g * 4 + u * 128;
            float4 vv;
            vv.x = ob[pl * 576 + ((f0 + 0) >> 3) * 9 + ((f0 + 0) & 7)];
            vv.y = ob[pl * 576 + ((f0 + 1) >> 3) * 9 + ((f0 + 1) & 7)];
            vv.z = ob[pl * 576 + ((f0 + 2) >> 3) * 9 + ((f0 + 2) & 7)];
            vv.w = ob[pl * 576 + ((f0 + 3) >> 3) * 9 + ((f0 + 3) & 7)];
            *(float4*)&orow[f0] = vv;
        }
    }
}

extern "C" void kernel_launch(void* const* d_in, const int* in_sizes, int n_in,
                              void* d_out, int out_size, void* d_ws, size_t ws_size,
                              hipStream_t stream)
{
    const float* Q = (const float*)d_in[0];
    const float* K = (const float*)d_in[1];
    const float* V = (const float*)d_in[2];
    const unsigned char* mask = (const unsigned char*)d_in[3];
    float* out = (float*)d_out;
    float* ws  = (float*)d_ws;

    // partial needs kchunks * 4096 * 64 * 4 bytes = kchunks MiB
    int kchunks = 64;
    while (kchunks > 1 &&
           (size_t)kchunks * 4096 * 64 * sizeof(float) > ws_size)
        kchunks >>= 1;
    const int clen = 8192 / kchunks;

    // ch fastest: resident blocks cover 64 ch x 8 bn -> 16 dense streams.
    qk_mfma_kernel<<<dim3(kchunks, 64), 1024, 0, stream>>>(Q, K, ws, clen);
    softmax_kernel<<<1024, 256, 0, stream>>>(ws, mask, kchunks);
    pv_mfma_kernel<<<dim3(128, 8), 512, 0, stream>>>(V, ws, out);
}

// Round 12
// 142.516 us; speedup vs baseline: 1.0930x; 1.0930x over previous
//
#include <hip/hip_runtime.h>
#include <hip/hip_bf16.h>
#include <cstdint>
#include <cstddef>

// Shapes: b=8, n=8, p=q=64, x=32, y=32, d=8  -> xyd = x*256+y*8+d in [0,8192)
// Q,K,V: [bn=64][64][8192] fp32.  out: [b][p][xyd][n] fp32 (transposed).
// scores[bn][p][q] = dot_k(Q,K)/1024 -> softmax over q -> out = attn @ V.
//
// R10: ch-fastest grid -> 93us qk (+21%). R11: fewer streams = null, and
// kchunks=64 regressed softmax. This round: R10 config + bijective XCD
// swizzle (T1): each XCD owns a contiguous 8-bn window so its private L2
// sees a dense sweep instead of scattered pieces of all 64 bn regions.

typedef __attribute__((ext_vector_type(4))) float f32x4;
typedef __attribute__((ext_vector_type(8))) short bf16x8;
typedef __attribute__((ext_vector_type(4))) short shortx4;

__device__ __forceinline__ unsigned short f2bf(float x) {
    unsigned int u = __builtin_bit_cast(unsigned int, x);
    u += 0x7FFFu + ((u >> 16) & 1u);     // RTNE
    return (unsigned short)(u >> 16);
}

__device__ __forceinline__ bf16x8 pack8(float4 lo, float4 hi) {
    bf16x8 f;
    f[0] = (short)f2bf(lo.x); f[1] = (short)f2bf(lo.y);
    f[2] = (short)f2bf(lo.z); f[3] = (short)f2bf(lo.w);
    f[4] = (short)f2bf(hi.x); f[5] = (short)f2bf(hi.y);
    f[6] = (short)f2bf(hi.z); f[7] = (short)f2bf(hi.w);
    return f;
}

// ---------------- Kernel A: partial QK^T via bf16 MFMA (R10 structure) ----
// 1-D grid of kchunks*64 blocks, 1024 threads = 16 waves.
// XCD-chunked swizzle: xcd = lin&7 owns bn in [xcd*8, xcd*8+8); within an
// XCD, ch varies fastest -> resident blocks sweep full rows densely.
// Per phase (256 k): thread bursts 8x float4 (64B Q + 64B K), bf16-pack into
// XOR-swizzled LDS [64][256] tiles, one barrier, 8 MFMA k-steps.
// partial[ch][bn][p][q]
__global__ __launch_bounds__(1024) void qk_mfma_kernel(
    const float* __restrict__ Q, const float* __restrict__ K,
    float* __restrict__ partial, int clen, int kchunks)
{
    __shared__ unsigned short Qs[64 * 256];   // 32 KiB bf16 [row][k]
    __shared__ unsigned short Ks[64 * 256];   // 32 KiB

    const int lin  = blockIdx.x;
    const int xcd  = lin & 7;
    const int idx  = lin >> 3;
    const int ch   = idx % kchunks;                 // fastest within XCD
    const int bn   = xcd * 8 + idx / kchunks;       // contiguous 8-bn window
    const int tid  = threadIdx.x;
    const int w    = tid >> 6;
    const int lane = tid & 63;
    const int wr   = w >> 2;            // p-tile 0..3
    const int wc   = w & 3;             // q-tile 0..3
    const int frow = lane & 15;
    const int kg   = lane >> 4;         // 0..3

    const float* Qb = Q + (size_t)bn * 64 * 8192 + (size_t)ch * clen;
    const float* Kb = K + (size_t)bn * 64 * 8192 + (size_t)ch * clen;

    const int srow = tid >> 4;          // staged row 0..63
    const int sc   = (tid & 15) * 16;   // float col base: thread covers 64B
    const int nph  = clen >> 8;         // phases of 256 k (1 when kchunks=32)

    f32x4 acc = (f32x4)(0.f);
    const int arow = wr * 16 + frow;
    const int brow = wc * 16 + frow;

    #pragma unroll 1
    for (int ph = 0; ph < nph; ++ph) {
        const float4* qp = (const float4*)(Qb + (size_t)srow * 8192 + ph * 256 + sc);
        const float4* kp = (const float4*)(Kb + (size_t)srow * 8192 + ph * 256 + sc);
        const float4 q0 = qp[0], q1 = qp[1], q2 = qp[2], q3 = qp[3];
        const float4 k0 = kp[0], k1 = kp[1], k2 = kp[2], k3 = kp[3];
        if (ph) __syncthreads();        // protect prior phase's LDS reads
        // 16B-slot swizzle: slot' = slot ^ (row&7)  (32 slots of 16B per row)
        const int sl0 = ((tid & 15) * 2    ) ^ (srow & 7);
        const int sl1 = ((tid & 15) * 2 + 1) ^ (srow & 7);
        *(bf16x8*)(Qs + srow * 256 + sl0 * 8) = pack8(q0, q1);
        *(bf16x8*)(Qs + srow * 256 + sl1 * 8) = pack8(q2, q3);
        *(bf16x8*)(Ks + srow * 256 + sl0 * 8) = pack8(k0, k1);
        *(bf16x8*)(Ks + srow * 256 + sl1 * 8) = pack8(k2, k3);
        __syncthreads();
        #pragma unroll
        for (int ks = 0; ks < 8; ++ks) {
            const bf16x8 a = *(const bf16x8*)(Qs + arow * 256 +
                                (((ks * 4 + kg) ^ (arow & 7)) * 8));
            const bf16x8 b = *(const bf16x8*)(Ks + brow * 256 +
                                (((ks * 4 + kg) ^ (brow & 7)) * 8));
            acc = __builtin_amdgcn_mfma_f32_16x16x32_bf16(a, b, acc, 0, 0, 0);
        }
    }

    // D layout: col = lane&15 (q), row = kg*4 + r (p)
    float* pb = partial + ((size_t)ch * 64 + bn) * 4096;
    const int p0 = wr * 16 + kg * 4;
    const int q0 = wc * 16 + frow;
    #pragma unroll
    for (int r = 0; r < 4; ++r)
        pb[(size_t)(p0 + r) * 64 + q0] = acc[r];
}

// ---------------- Kernel B: reduce partials + softmax (unchanged) ----------------
__global__ __launch_bounds__(256) void softmax_kernel(
    float* __restrict__ ws, const unsigned char* __restrict__ mask, int kchunks)
{
    const int row  = blockIdx.x * 4 + (threadIdx.x >> 6);
    const int q    = threadIdx.x & 63;
    float s = 0.f;
    for (int c = 0; c < kchunks; ++c)
        s += ws[((size_t)c * 4096 + row) * 64 + q];
    s *= (1.0f / 1024.0f);
    const int b = row >> 9;
    if (mask[b * 64 + q]) s = -__builtin_inff();
    float m = s;
    #pragma unroll
    for (int off = 32; off; off >>= 1) m = fmaxf(m, __shfl_xor(m, off));
    const float e = __expf(s - m);
    float sum = e;
    #pragma unroll
    for (int off = 32; off; off >>= 1) sum += __shfl_xor(sum, off);
    ws[(size_t)row * 64 + q] = e / sum;
}

// ---------------- Kernel C: PV via bf16 MFMA (unchanged, proven) ----------------
__global__ __launch_bounds__(512, 2) void pv_mfma_kernel(
    const float* __restrict__ V, const float* __restrict__ attn,
    float* __restrict__ out)
{
    __shared__ unsigned char smem[65536];   // phase 1: vt[8][64][64] bf16; phase 2: ob fp32

    const int b     = blockIdx.y;
    const int chunk = blockIdx.x;
    const int tid   = threadIdx.x;
    const int w     = tid >> 6;           // wave = n
    const int lane  = tid & 63;

    const float* Vb = V    + (size_t)(b * 8 + w) * 64 * 8192 + (size_t)chunk * 64;
    const float* Ab = attn + (size_t)(b * 8 + w) * 4096;

    unsigned short* vtn = (unsigned short*)smem + w * 4096;   // this wave's V^T tile

    // ---- stage V chunk -> LDS transposed bf16, swizzled ----
    const int c  = lane >> 2;
    const int qg = lane & 3;
    #pragma unroll
    for (int s = 0; s < 4; ++s) {
        const int q0 = s * 16 + qg * 4;
        const float4 r0 = *(const float4*)&Vb[(size_t)(q0 + 0) * 8192 + c * 4];
        const float4 r1 = *(const float4*)&Vb[(size_t)(q0 + 1) * 8192 + c * 4];
        const float4 r2 = *(const float4*)&Vb[(size_t)(q0 + 2) * 8192 + c * 4];
        const float4 r3 = *(const float4*)&Vb[(size_t)(q0 + 3) * 8192 + c * 4];
        const float v0[4] = {r0.x, r0.y, r0.z, r0.w};
        const float v1[4] = {r1.x, r1.y, r1.z, r1.w};
        const float v2[4] = {r2.x, r2.y, r2.z, r2.w};
        const float v3[4] = {r3.x, r3.y, r3.z, r3.w};
        #pragma unroll
        for (int cc = 0; cc < 4; ++cc) {
            const int row = c * 4 + cc;       // xc within chunk
            shortx4 pk;
            pk.x = (short)f2bf(v0[cc]);
            pk.y = (short)f2bf(v1[cc]);
            pk.z = (short)f2bf(v2[cc]);
            pk.w = (short)f2bf(v3[cc]);
            const int soff = row * 64 + (q0 ^ ((row & 7) << 3) ^ (((row >> 3) & 3) << 4));
            *(shortx4*)(vtn + soff) = pk;
        }
    }

    // ---- A fragments: attn rows, bf16 ----
    const int arow = lane & 15;
    const int q0a  = (lane >> 4) * 8;
    bf16x8 afrag[4][2];
    #pragma unroll
    for (int mt = 0; mt < 4; ++mt) {
        #pragma unroll
        for (int ks = 0; ks < 2; ++ks) {
            const float* ap = Ab + (mt * 16 + arow) * 64 + ks * 32 + q0a;
            const float4 lo = *(const float4*)ap;
            const float4 hi = *(const float4*)(ap + 4);
            afrag[mt][ks] = pack8(lo, hi);
        }
    }

    // ---- MFMA compute ----
    f32x4 acc[4][4];
    #pragma unroll
    for (int mt = 0; mt < 4; ++mt)
        #pragma unroll
        for (int nt = 0; nt < 4; ++nt)
            acc[mt][nt] = (f32x4)(0.f);

    const int bcol = lane & 15;
    const int q0b  = (lane >> 4) * 8;
    #pragma unroll
    for (int nt = 0; nt < 4; ++nt) {
        bf16x8 bfr[2];
        #pragma unroll
        for (int ks = 0; ks < 2; ++ks) {
            const int row  = nt * 16 + bcol;
            const int q0   = ks * 32 + q0b;
            const int soff = row * 64 + (q0 ^ ((row & 7) << 3) ^ (((row >> 3) & 3) << 4));
            bfr[ks] = *(const bf16x8*)(vtn + soff);
        }
        #pragma unroll
        for (int ks = 0; ks < 2; ++ks)
            #pragma unroll
            for (int mt = 0; mt < 4; ++mt)
                acc[mt][nt] = __builtin_amdgcn_mfma_f32_16x16x32_bf16(
                    afrag[mt][ks], bfr[ks], acc[mt][nt], 0, 0, 0);
    }

    // ---- store: D frags -> LDS transpose -> coalesced float4 stores ----
    float* ob = (float*)smem;          // [16 p][64 xc][9 (8n + pad)]
    const int pq = lane >> 4;
    const int pl = tid >> 5;           // 0..15 : p-row for store phase
    const int g  = tid & 31;
    #pragma unroll
    for (int mt = 0; mt < 4; ++mt) {
        __syncthreads();
        #pragma unroll
        for (int nt = 0; nt < 4; ++nt)
            #pragma unroll
            for (int r = 0; r < 4; ++r) {
                const int prow = pq * 4 + r;
                const int xc   = nt * 16 + (lane & 15);
                ob[prow * 576 + xc * 9 + w] = acc[mt][nt][r];
            }
        __syncthreads();
        float* orow = out + (size_t)b * 4194304 + (size_t)(mt * 16 + pl) * 65536
                          + (size_t)chunk * 512;
        #pragma unroll
        for (int u = 0; u < 4; ++u) {
            const int f0 = g * 4 + u * 128;
            float4 vv;
            vv.x = ob[pl * 576 + ((f0 + 0) >> 3) * 9 + ((f0 + 0) & 7)];
            vv.y = ob[pl * 576 + ((f0 + 1) >> 3) * 9 + ((f0 + 1) & 7)];
            vv.z = ob[pl * 576 + ((f0 + 2) >> 3) * 9 + ((f0 + 2) & 7)];
            vv.w = ob[pl * 576 + ((f0 + 3) >> 3) * 9 + ((f0 + 3) & 7)];
            *(float4*)&orow[f0] = vv;
        }
    }
}

extern "C" void kernel_launch(void* const* d_in, const int* in_sizes, int n_in,
                              void* d_out, int out_size, void* d_ws, size_t ws_size,
                              hipStream_t stream)
{
    const float* Q = (const float*)d_in[0];
    const float* K = (const float*)d_in[1];
    const float* V = (const float*)d_in[2];
    const unsigned char* mask = (const unsigned char*)d_in[3];
    float* out = (float*)d_out;
    float* ws  = (float*)d_ws;

    // partial needs kchunks * 4096 * 64 * 4 bytes = kchunks MiB
    int kchunks = 32;
    while (kchunks > 1 &&
           (size_t)kchunks * 4096 * 64 * sizeof(float) > ws_size)
        kchunks >>= 1;
    const int clen = 8192 / kchunks;

    // 1-D grid, XCD-chunked swizzle inside the kernel (bijective for pow2).
    qk_mfma_kernel<<<kchunks * 64, 1024, 0, stream>>>(Q, K, ws, clen, kchunks);
    softmax_kernel<<<1024, 256, 0, stream>>>(ws, mask, kchunks);
    pv_mfma_kernel<<<dim3(128, 8), 512, 0, stream>>>(V, ws, out);
}

// Round 14
// 127.188 us; speedup vs baseline: 1.2247x; 1.1205x over previous
//
#include <hip/hip_runtime.h>
#include <hip/hip_bf16.h>
#include <cstdint>
#include <cstddef>

// Shapes: b=8, n=8, p=q=64, x=32, y=32, d=8  -> xyd = x*256+y*8+d in [0,8192)
// Q,K,V: [bn=64][64][8192] fp32.  out: [b][p][xyd][n] fp32 (transposed).
// scores[bn][p][q] = dot_k(Q,K)/1024 -> softmax over q -> out = attn @ V.
//
// R12 insight: qk already gets ~50% L3 hits (FETCH 131 MB vs 256 MB read);
// its 93us is the HBM-miss half at ~1.75 TB/s. pv's V-read (128 MB) and
// out-write (128 MB) are touched-once dead traffic that evicts Q+K from L3
// between graph replays. NT hints on V loads / out stores (typed as
// ext_vector f32x4 -- the HIP float4 wrapper is rejected by the builtin).

typedef __attribute__((ext_vector_type(4))) float f32x4;
typedef __attribute__((ext_vector_type(8))) short bf16x8;
typedef __attribute__((ext_vector_type(4))) short shortx4;

__device__ __forceinline__ unsigned short f2bf(float x) {
    unsigned int u = __builtin_bit_cast(unsigned int, x);
    u += 0x7FFFu + ((u >> 16) & 1u);     // RTNE
    return (unsigned short)(u >> 16);
}

__device__ __forceinline__ bf16x8 pack8(float4 lo, float4 hi) {
    bf16x8 f;
    f[0] = (short)f2bf(lo.x); f[1] = (short)f2bf(lo.y);
    f[2] = (short)f2bf(lo.z); f[3] = (short)f2bf(lo.w);
    f[4] = (short)f2bf(hi.x); f[5] = (short)f2bf(hi.y);
    f[6] = (short)f2bf(hi.z); f[7] = (short)f2bf(hi.w);
    return f;
}

__device__ __forceinline__ bf16x8 pack8v(f32x4 lo, f32x4 hi) {
    bf16x8 f;
    f[0] = (short)f2bf(lo[0]); f[1] = (short)f2bf(lo[1]);
    f[2] = (short)f2bf(lo[2]); f[3] = (short)f2bf(lo[3]);
    f[4] = (short)f2bf(hi[0]); f[5] = (short)f2bf(hi[1]);
    f[6] = (short)f2bf(hi[2]); f[7] = (short)f2bf(hi[3]);
    return f;
}

// ---------------- Kernel A: partial QK^T via bf16 MFMA (R10 structure) ----
// grid (ch=kchunks FASTEST, bn=64), 1024 threads = 16 waves.
// Per phase (256 k): thread bursts 8x float4 (64B Q + 64B K), bf16-pack into
// XOR-swizzled LDS [64][256] tiles, one barrier, 8 MFMA k-steps.
// Q/K loads are NORMAL (cached) - we want them L3-resident across replays.
// partial[ch][bn][p][q]
__global__ __launch_bounds__(1024) void qk_mfma_kernel(
    const float* __restrict__ Q, const float* __restrict__ K,
    float* __restrict__ partial, int clen)
{
    __shared__ unsigned short Qs[64 * 256];   // 32 KiB bf16 [row][k]
    __shared__ unsigned short Ks[64 * 256];   // 32 KiB

    const int ch   = blockIdx.x;        // FASTEST: dense cross-block frontier
    const int bn   = blockIdx.y;
    const int tid  = threadIdx.x;
    const int w    = tid >> 6;
    const int lane = tid & 63;
    const int wr   = w >> 2;            // p-tile 0..3
    const int wc   = w & 3;             // q-tile 0..3
    const int frow = lane & 15;
    const int kg   = lane >> 4;         // 0..3

    const float* Qb = Q + (size_t)bn * 64 * 8192 + (size_t)ch * clen;
    const float* Kb = K + (size_t)bn * 64 * 8192 + (size_t)ch * clen;

    const int srow = tid >> 4;          // staged row 0..63
    const int sc   = (tid & 15) * 16;   // float col base: thread covers 64B
    const int nph  = clen >> 8;         // phases of 256 k (1 when kchunks=32)

    f32x4 acc = (f32x4)(0.f);
    const int arow = wr * 16 + frow;
    const int brow = wc * 16 + frow;

    #pragma unroll 1
    for (int ph = 0; ph < nph; ++ph) {
        const float4* qp = (const float4*)(Qb + (size_t)srow * 8192 + ph * 256 + sc);
        const float4* kp = (const float4*)(Kb + (size_t)srow * 8192 + ph * 256 + sc);
        const float4 q0 = qp[0], q1 = qp[1], q2 = qp[2], q3 = qp[3];
        const float4 k0 = kp[0], k1 = kp[1], k2 = kp[2], k3 = kp[3];
        if (ph) __syncthreads();        // protect prior phase's LDS reads
        // 16B-slot swizzle: slot' = slot ^ (row&7)  (32 slots of 16B per row)
        const int sl0 = ((tid & 15) * 2    ) ^ (srow & 7);
        const int sl1 = ((tid & 15) * 2 + 1) ^ (srow & 7);
        *(bf16x8*)(Qs + srow * 256 + sl0 * 8) = pack8(q0, q1);
        *(bf16x8*)(Qs + srow * 256 + sl1 * 8) = pack8(q2, q3);
        *(bf16x8*)(Ks + srow * 256 + sl0 * 8) = pack8(k0, k1);
        *(bf16x8*)(Ks + srow * 256 + sl1 * 8) = pack8(k2, k3);
        __syncthreads();
        #pragma unroll
        for (int ks = 0; ks < 8; ++ks) {
            const bf16x8 a = *(const bf16x8*)(Qs + arow * 256 +
                                (((ks * 4 + kg) ^ (arow & 7)) * 8));
            const bf16x8 b = *(const bf16x8*)(Ks + brow * 256 +
                                (((ks * 4 + kg) ^ (brow & 7)) * 8));
            acc = __builtin_amdgcn_mfma_f32_16x16x32_bf16(a, b, acc, 0, 0, 0);
        }
    }

    // D layout: col = lane&15 (q), row = kg*4 + r (p)
    float* pb = partial + ((size_t)ch * 64 + bn) * 4096;
    const int p0 = wr * 16 + kg * 4;
    const int q0 = wc * 16 + frow;
    #pragma unroll
    for (int r = 0; r < 4; ++r)
        pb[(size_t)(p0 + r) * 64 + q0] = acc[r];
}

// ---------------- Kernel B: reduce partials + softmax (unchanged) ----------------
__global__ __launch_bounds__(256) void softmax_kernel(
    float* __restrict__ ws, const unsigned char* __restrict__ mask, int kchunks)
{
    const int row  = blockIdx.x * 4 + (threadIdx.x >> 6);
    const int q    = threadIdx.x & 63;
    float s = 0.f;
    for (int c = 0; c < kchunks; ++c)
        s += ws[((size_t)c * 4096 + row) * 64 + q];
    s *= (1.0f / 1024.0f);
    const int b = row >> 9;
    if (mask[b * 64 + q]) s = -__builtin_inff();
    float m = s;
    #pragma unroll
    for (int off = 32; off; off >>= 1) m = fmaxf(m, __shfl_xor(m, off));
    const float e = __expf(s - m);
    float sum = e;
    #pragma unroll
    for (int off = 32; off; off >>= 1) sum += __shfl_xor(sum, off);
    ws[(size_t)row * 64 + q] = e / sum;
}

// ---------------- Kernel C: PV via bf16 MFMA + NT hints ----------------
// V loads and out stores are nontemporal (ext_vector f32x4): touched exactly
// once, must not evict Q/K from L3 between graph replays.
__global__ __launch_bounds__(512, 2) void pv_mfma_kernel(
    const float* __restrict__ V, const float* __restrict__ attn,
    float* __restrict__ out)
{
    __shared__ unsigned char smem[65536];   // phase 1: vt[8][64][64] bf16; phase 2: ob fp32

    const int b     = blockIdx.y;
    const int chunk = blockIdx.x;
    const int tid   = threadIdx.x;
    const int w     = tid >> 6;           // wave = n
    const int lane  = tid & 63;

    const float* Vb = V    + (size_t)(b * 8 + w) * 64 * 8192 + (size_t)chunk * 64;
    const float* Ab = attn + (size_t)(b * 8 + w) * 4096;

    unsigned short* vtn = (unsigned short*)smem + w * 4096;   // this wave's V^T tile

    // ---- stage V chunk -> LDS transposed bf16, swizzled (NT loads) ----
    const int c  = lane >> 2;
    const int qg = lane & 3;
    #pragma unroll
    for (int s = 0; s < 4; ++s) {
        const int q0 = s * 16 + qg * 4;
        const f32x4 r0 = __builtin_nontemporal_load((const f32x4*)&Vb[(size_t)(q0 + 0) * 8192 + c * 4]);
        const f32x4 r1 = __builtin_nontemporal_load((const f32x4*)&Vb[(size_t)(q0 + 1) * 8192 + c * 4]);
        const f32x4 r2 = __builtin_nontemporal_load((const f32x4*)&Vb[(size_t)(q0 + 2) * 8192 + c * 4]);
        const f32x4 r3 = __builtin_nontemporal_load((const f32x4*)&Vb[(size_t)(q0 + 3) * 8192 + c * 4]);
        #pragma unroll
        for (int cc = 0; cc < 4; ++cc) {
            const int row = c * 4 + cc;       // xc within chunk
            shortx4 pk;
            pk.x = (short)f2bf(r0[cc]);
            pk.y = (short)f2bf(r1[cc]);
            pk.z = (short)f2bf(r2[cc]);
            pk.w = (short)f2bf(r3[cc]);
            const int soff = row * 64 + (q0 ^ ((row & 7) << 3) ^ (((row >> 3) & 3) << 4));
            *(shortx4*)(vtn + soff) = pk;
        }
    }

    // ---- A fragments: attn rows, bf16 (normal loads: attn is hot) ----
    const int arow = lane & 15;
    const int q0a  = (lane >> 4) * 8;
    bf16x8 afrag[4][2];
    #pragma unroll
    for (int mt = 0; mt < 4; ++mt) {
        #pragma unroll
        for (int ks = 0; ks < 2; ++ks) {
            const float* ap = Ab + (mt * 16 + arow) * 64 + ks * 32 + q0a;
            const float4 lo = *(const float4*)ap;
            const float4 hi = *(const float4*)(ap + 4);
            afrag[mt][ks] = pack8(lo, hi);
        }
    }

    // ---- MFMA compute ----
    f32x4 acc[4][4];
    #pragma unroll
    for (int mt = 0; mt < 4; ++mt)
        #pragma unroll
        for (int nt = 0; nt < 4; ++nt)
            acc[mt][nt] = (f32x4)(0.f);

    const int bcol = lane & 15;
    const int q0b  = (lane >> 4) * 8;
    #pragma unroll
    for (int nt = 0; nt < 4; ++nt) {
        bf16x8 bfr[2];
        #pragma unroll
        for (int ks = 0; ks < 2; ++ks) {
            const int row  = nt * 16 + bcol;
            const int q0   = ks * 32 + q0b;
            const int soff = row * 64 + (q0 ^ ((row & 7) << 3) ^ (((row >> 3) & 3) << 4));
            bfr[ks] = *(const bf16x8*)(vtn + soff);
        }
        #pragma unroll
        for (int ks = 0; ks < 2; ++ks)
            #pragma unroll
            for (int mt = 0; mt < 4; ++mt)
                acc[mt][nt] = __builtin_amdgcn_mfma_f32_16x16x32_bf16(
                    afrag[mt][ks], bfr[ks], acc[mt][nt], 0, 0, 0);
    }

    // ---- store: D frags -> LDS transpose -> coalesced NT float4 stores ----
    float* ob = (float*)smem;          // [16 p][64 xc][9 (8n + pad)]
    const int pq = lane >> 4;
    const int pl = tid >> 5;           // 0..15 : p-row for store phase
    const int g  = tid & 31;
    #pragma unroll
    for (int mt = 0; mt < 4; ++mt) {
        __syncthreads();
        #pragma unroll
        for (int nt = 0; nt < 4; ++nt)
            #pragma unroll
            for (int r = 0; r < 4; ++r) {
                const int prow = pq * 4 + r;
                const int xc   = nt * 16 + (lane & 15);
                ob[prow * 576 + xc * 9 + w] = acc[mt][nt][r];
            }
        __syncthreads();
        float* orow = out + (size_t)b * 4194304 + (size_t)(mt * 16 + pl) * 65536
                          + (size_t)chunk * 512;
        #pragma unroll
        for (int u = 0; u < 4; ++u) {
            const int f0 = g * 4 + u * 128;
            f32x4 vv;
            vv[0] = ob[pl * 576 + ((f0 + 0) >> 3) * 9 + ((f0 + 0) & 7)];
            vv[1] = ob[pl * 576 + ((f0 + 1) >> 3) * 9 + ((f0 + 1) & 7)];
            vv[2] = ob[pl * 576 + ((f0 + 2) >> 3) * 9 + ((f0 + 2) & 7)];
            vv[3] = ob[pl * 576 + ((f0 + 3) >> 3) * 9 + ((f0 + 3) & 7)];
            __builtin_nontemporal_store(vv, (f32x4*)&orow[f0]);
        }
    }
}

extern "C" void kernel_launch(void* const* d_in, const int* in_sizes, int n_in,
                              void* d_out, int out_size, void* d_ws, size_t ws_size,
                              hipStream_t stream)
{
    const float* Q = (const float*)d_in[0];
    const float* K = (const float*)d_in[1];
    const float* V = (const float*)d_in[2];
    const unsigned char* mask = (const unsigned char*)d_in[3];
    float* out = (float*)d_out;
    float* ws  = (float*)d_ws;

    // partial needs kchunks * 4096 * 64 * 4 bytes = kchunks MiB
    int kchunks = 32;
    while (kchunks > 1 &&
           (size_t)kchunks * 4096 * 64 * sizeof(float) > ws_size)
        kchunks >>= 1;
    const int clen = 8192 / kchunks;

    // R10-best grid: ch fastest -> dense cross-block DRAM streams.
    qk_mfma_kernel<<<dim3(kchunks, 64), 1024, 0, stream>>>(Q, K, ws, clen);
    softmax_kernel<<<1024, 256, 0, stream>>>(ws, mask, kchunks);
    pv_mfma_kernel<<<dim3(128, 8), 512, 0, stream>>>(V, ws, out);
}